// Round 12
// baseline (869.787 us; speedup 1.0000x reference)
//
#include <hip/hip_runtime.h>

#define HD 32    // hidden/emb dim
#define ND 16    // node feature dim
#define ED 8     // edge feature dim
#define NCHK 256 // edge-stream chunks per list
#define MAXLB 2048  // max histogram bins in LDS
#define BKV 128  // v-nodes per bucket (shift 7)
#define BKA 8    // a-nodes per bucket (shift 3)

// ---------------- bf16 pack/unpack helpers ----------------
__device__ __forceinline__ unsigned bf16rne(float f) {
    unsigned u = __float_as_uint(f);
    return (u + 0x7fffu + ((u >> 16) & 1u)) >> 16;
}
__device__ __forceinline__ unsigned packbf2(float lo, float hi) {
    return bf16rne(lo) | (bf16rne(hi) << 16);
}
__device__ __forceinline__ void unpack8(uint4 r, float* p) {
    p[0] = __uint_as_float(r.x << 16); p[1] = __uint_as_float(r.x & 0xffff0000u);
    p[2] = __uint_as_float(r.y << 16); p[3] = __uint_as_float(r.y & 0xffff0000u);
    p[4] = __uint_as_float(r.z << 16); p[5] = __uint_as_float(r.z & 0xffff0000u);
    p[6] = __uint_as_float(r.w << 16); p[7] = __uint_as_float(r.w & 0xffff0000u);
}

// ===========================================================================
// Standalone channel-parallel precompute.
//  PXg[v]=gvb1+xv.gvW1[0:16] (f32)  PXh[v] (f32)  PXga[a] (f32)
//  PCg16[c]=bf16(xc.gvW1[16:32])    PAh16[a]=bf16(xa.hvW1[16:32])
//  Mg=gvW2@fvW1[16:48], bg; Mh,bh; Mga=gaW2@faW1[16:48], bga;
//  Nfv=fvW2@gaW1[16:48], bfv
// ===========================================================================
__global__ __launch_bounds__(256) void precompC_kernel(
    const float* __restrict__ xv, const float* __restrict__ xc, const float* __restrict__ xa,
    const float* __restrict__ gvW1, const float* __restrict__ gvb1,
    const float* __restrict__ hvW1, const float* __restrict__ hvb1,
    const float* __restrict__ gaW1, const float* __restrict__ gab1,
    const float* __restrict__ gvW2, const float* __restrict__ gvb2,
    const float* __restrict__ hvW2, const float* __restrict__ hvb2,
    const float* __restrict__ gaW2, const float* __restrict__ gab2,
    const float* __restrict__ fvW1, const float* __restrict__ fvW2,
    const float* __restrict__ fvb2, const float* __restrict__ faW1,
    float* __restrict__ PXg, float* __restrict__ PXh, float* __restrict__ PXga,
    unsigned* __restrict__ PCg16, unsigned* __restrict__ PAh16,
    float* __restrict__ Mg, float* __restrict__ bg,
    float* __restrict__ Mh, float* __restrict__ bh,
    float* __restrict__ Mga, float* __restrict__ bga,
    float* __restrict__ Nfv, float* __restrict__ bfv,
    int nV, int nC, int nA)
{
    int bV = (nV * 32 + 255) / 256, bC = (nC * 32 + 255) / 256, bA = (nA * 32 + 255) / 256;
    int b = blockIdx.x;
    int tid = threadIdx.x;
    int ch = tid & 31;
    __shared__ float s0[512], s1[512];

    if (b < bV) {
        for (int i = tid; i < 512; i += 256) { s0[i] = gvW1[i]; s1[i] = hvW1[i]; }
        __syncthreads();
        int v = (b * 256 + tid) >> 5;
        if (v >= nV) return;
        float x = (ch < ND) ? xv[(size_t)v * ND + ch] : 0.f;
        float pg = gvb1[ch], ph = hvb1[ch];
#pragma unroll
        for (int i = 0; i < ND; i++) {
            float xi = __shfl(x, i, 32);
            pg = fmaf(xi, s0[i * 32 + ch], pg);
            ph = fmaf(xi, s1[i * 32 + ch], ph);
        }
        PXg[(size_t)v * 32 + ch] = pg;
        PXh[(size_t)v * 32 + ch] = ph;
    } else if (b < bV + bC) {
        for (int i = tid; i < 512; i += 256) s0[i] = gvW1[512 + i];
        __syncthreads();
        int c = ((b - bV) * 256 + tid) >> 5;
        if (c >= nC) return;
        float x = (ch < ND) ? xc[(size_t)c * ND + ch] : 0.f;
        float p = 0.f;
#pragma unroll
        for (int i = 0; i < ND; i++) p = fmaf(__shfl(x, i, 32), s0[i * 32 + ch], p);
        float hi = __shfl_xor(p, 1, 32);
        if (!(ch & 1)) PCg16[(size_t)c * 16 + (ch >> 1)] = packbf2(p, hi);
    } else if (b < bV + bC + bA) {
        for (int i = tid; i < 512; i += 256) { s0[i] = hvW1[512 + i]; s1[i] = gaW1[i]; }
        __syncthreads();
        int a = ((b - bV - bC) * 256 + tid) >> 5;
        if (a >= nA) return;
        float x = (ch < ND) ? xa[(size_t)a * ND + ch] : 0.f;
        float ph = 0.f, pg = gab1[ch];
#pragma unroll
        for (int i = 0; i < ND; i++) {
            float xi = __shfl(x, i, 32);
            ph = fmaf(xi, s0[i * 32 + ch], ph);
            pg = fmaf(xi, s1[i * 32 + ch], pg);
        }
        float hi = __shfl_xor(ph, 1, 32);
        if (!(ch & 1)) PAh16[(size_t)a * 16 + (ch >> 1)] = packbf2(ph, hi);
        PXga[(size_t)a * 32 + ch] = pg;
    } else {
        int m = b - (bV + bC + bA);
        const float *W2, *b2, *T; float *M, *bb; int toff;
        if (m == 0)      { W2 = gvW2; b2 = gvb2; T = fvW1; toff = ND;      M = Mg;  bb = bg;  }
        else if (m == 1) { W2 = hvW2; b2 = hvb2; T = fvW1; toff = ND + HD; M = Mh;  bb = bh;  }
        else if (m == 2) { W2 = gaW2; b2 = gab2; T = faW1; toff = ND;      M = Mga; bb = bga; }
        else             { W2 = fvW2; b2 = fvb2; T = gaW1; toff = ND;      M = Nfv; bb = bfv; }
        for (int idx = tid; idx < 1024; idx += 256) {
            int c = idx >> 5, h = idx & 31;
            float s = 0.f;
#pragma unroll
            for (int o = 0; o < HD; o++) s = fmaf(W2[c * HD + o], T[(toff + o) * HD + h], s);
            M[idx] = s;
        }
        if (tid < HD) {
            int h = tid;
            float s = 0.f;
#pragma unroll
            for (int o = 0; o < HD; o++) s = fmaf(b2[o], T[(toff + o) * HD + h], s);
            bb[h] = s;
        }
    }
}

// ===========================================================================
// Bucket histogram: per-chunk LDS count over ~800-1400 bins (read stream once).
// ===========================================================================
__global__ __launch_bounds__(256) void countB_kernel(
    const int* __restrict__ c2v_t, int* __restrict__ cntg, int nEC,
    const int* __restrict__ a2v_t, const int* __restrict__ a2v_s,
    int* __restrict__ cnth, int* __restrict__ cnta, int nEA,
    int nbg, int nbh, int nba)
{
    __shared__ int lcnt[MAXLB];
    int b = blockIdx.x, tid = threadIdx.x;
    if (b < NCHK) {
        int chunk = b;
        for (int i = tid; i < nbg; i += 256) lcnt[i] = 0;
        __syncthreads();
        int CH = ((nEC + NCHK - 1) / NCHK + 255) & ~255;
        int i0 = chunk * CH, i1 = min(i0 + CH, nEC);
        for (int i = i0 + tid; i < i1; i += 256)
            atomicAdd(&lcnt[c2v_t[i] >> 7], 1);
        __syncthreads();
        int* out = cntg + (size_t)chunk * nbg;
        for (int i = tid; i < nbg; i += 256) out[i] = lcnt[i];
    } else {
        int chunk = b - NCHK;
        for (int i = tid; i < nbh + nba; i += 256) lcnt[i] = 0;
        __syncthreads();
        int CH = ((nEA + NCHK - 1) / NCHK + 255) & ~255;
        int i0 = chunk * CH, i1 = min(i0 + CH, nEA);
        for (int i = i0 + tid; i < i1; i += 256) {
            atomicAdd(&lcnt[a2v_t[i] >> 7], 1);
            atomicAdd(&lcnt[nbh + (a2v_s[i] >> 3)], 1);
        }
        __syncthreads();
        int* outh = cnth + (size_t)chunk * nbh;
        for (int i = tid; i < nbh; i += 256) outh[i] = lcnt[i];
        int* outa = cnta + (size_t)chunk * nba;
        for (int i = tid; i < nba; i += 256) outa[i] = lcnt[nbh + i];
    }
}

// Bcnt[b] = sum over chunks; Boff initialized to same (scanned in place next).
__global__ __launch_bounds__(256) void bsum_kernel(
    const int* __restrict__ cntg, const int* __restrict__ cnth, const int* __restrict__ cnta,
    int* __restrict__ Bcnt, int* __restrict__ Boff, int nbg, int nbh, int nba)
{
    int i = blockIdx.x * 256 + threadIdx.x;
    int nb = nbg + nbh + nba;
    if (i >= nb) return;
    const int* cnt; int bin, stride;
    if (i < nbg)            { cnt = cntg; bin = i;             stride = nbg; }
    else if (i < nbg + nbh) { cnt = cnth; bin = i - nbg;       stride = nbh; }
    else                    { cnt = cnta; bin = i - nbg - nbh; stride = nba; }
    int s = 0;
    for (int c = 0; c < NCHK; c++) s += cnt[(size_t)c * stride + bin];
    Bcnt[i] = s; Boff[i] = s;
}

__device__ __forceinline__ void exscan_block(int* __restrict__ c, int n)
{
    int i = threadIdx.x;
    int v = (i < n) ? c[i] : 0;
    int x = v;
    int lane = i & 63, wid = i >> 6;
#pragma unroll
    for (int dd = 1; dd < 64; dd <<= 1) {
        int y = __shfl_up(x, dd, 64);
        if (lane >= dd) x += y;
    }
    __shared__ int ws[16];
    if (lane == 63) ws[wid] = x;
    __syncthreads();
    if (i == 0) {
        int a = 0;
#pragma unroll
        for (int w = 0; w < 16; w++) { int t = ws[w]; ws[w] = a; a += t; }
    }
    __syncthreads();
    int excl = ws[wid] + x - v;
    if (i < n) c[i] = excl;
}

__global__ __launch_bounds__(1024) void bscan_kernel(
    int* __restrict__ Boff, int nbg, int nbh, int nba)
{
    if (blockIdx.x == 0)      exscan_block(Boff, nbg);
    else if (blockIdx.x == 1) exscan_block(Boff + nbg, nbh);
    else                      exscan_block(Boff + nbg + nbh, nba);
}

// cnt[c][bin] <- Boff[bin] + prefix over chunks
__global__ __launch_bounds__(256) void bbase_kernel(
    int* __restrict__ cntg, int* __restrict__ cnth, int* __restrict__ cnta,
    const int* __restrict__ Boff, int nbg, int nbh, int nba)
{
    int i = blockIdx.x * 256 + threadIdx.x;
    int nb = nbg + nbh + nba;
    if (i >= nb) return;
    int* cnt; int bin, stride;
    if (i < nbg)            { cnt = cntg; bin = i;             stride = nbg; }
    else if (i < nbg + nbh) { cnt = cnth; bin = i - nbg;       stride = nbh; }
    else                    { cnt = cnta; bin = i - nbg - nbh; stride = nba; }
    int running = Boff[i];
    for (int c = 0; c < NCHK; c++) {
        int t = cnt[(size_t)c * stride + bin];
        cnt[(size_t)c * stride + bin] = running;
        running += t;
    }
}

// ===========================================================================
// Bucket scatter: slot = {packed_ids, eid}. Writes per (block,bucket) are
// contiguous ~64B runs -> ~1x write amplification. Stream read once.
//  g/h: packed = (src<<7)|(tgt&127)   a: packed = (tgt<<3)|(src&7)
// ===========================================================================
__global__ __launch_bounds__(256) void scatterBk_kernel(
    const int* __restrict__ c2v_t, const int* __restrict__ c2v_s,
    const int* __restrict__ cntg, int2* __restrict__ slot_g, int nEC,
    const int* __restrict__ a2v_t, const int* __restrict__ a2v_s,
    const int* __restrict__ cnth, const int* __restrict__ cnta,
    int2* __restrict__ slot_h, int2* __restrict__ slot_a, int nEA,
    int nbg, int nbh, int nba)
{
    __shared__ int lbase[MAXLB];
    int b = blockIdx.x, tid = threadIdx.x;
    if (b < NCHK) {
        int chunk = b;
        const int* src = cntg + (size_t)chunk * nbg;
        for (int i = tid; i < nbg; i += 256) lbase[i] = src[i];
        __syncthreads();
        int CH = ((nEC + NCHK - 1) / NCHK + 255) & ~255;
        int i0 = chunk * CH, i1 = min(i0 + CH, nEC);
        for (int i = i0 + tid; i < i1; i += 256) {
            int t = c2v_t[i], s = c2v_s[i];
            int p = atomicAdd(&lbase[t >> 7], 1);
            slot_g[p] = make_int2((s << 7) | (t & 127), i);
        }
    } else {
        int chunk = b - NCHK;
        const int* srch = cnth + (size_t)chunk * nbh;
        for (int i = tid; i < nbh; i += 256) lbase[i] = srch[i];
        const int* srca = cnta + (size_t)chunk * nba;
        for (int i = tid; i < nba; i += 256) lbase[nbh + i] = srca[i];
        __syncthreads();
        int CH = ((nEA + NCHK - 1) / NCHK + 255) & ~255;
        int i0 = chunk * CH, i1 = min(i0 + CH, nEA);
        for (int i = i0 + tid; i < i1; i += 256) {
            int t = a2v_t[i], s = a2v_s[i];
            int p = atomicAdd(&lbase[t >> 7], 1);
            slot_h[p] = make_int2((s << 7) | (t & 127), i);
            int q = atomicAdd(&lbase[nbh + (s >> 3)], 1);
            slot_a[q] = make_int2((t << 3) | (s & 7), i);
        }
    }
}

// ===========================================================================
// fv accumulate: one block per 128-node bucket (g buckets then h buckets).
// LDS: acc[128][33] (+ pad kills bank conflicts), preloaded PX rows, ea-rows
// of W1. Per edge: 32ch relu contribution, LDS atomicAdd. Writes Ag/deg
// coalesced. Zero global atomics.
// ===========================================================================
__global__ __launch_bounds__(256) void fvacc_kernel(
    const int2* __restrict__ slot_g, const int2* __restrict__ slot_h,
    const unsigned* __restrict__ PCg16, const unsigned* __restrict__ PAh16,
    const float* __restrict__ ea_c, const float* __restrict__ ea_a,
    const float* __restrict__ PXg, const float* __restrict__ PXh,
    const float* __restrict__ gvW1, const float* __restrict__ hvW1,
    const int* __restrict__ Boff, const int* __restrict__ Bcnt,
    float* __restrict__ Ag, float* __restrict__ Ah,
    int* __restrict__ deg_g, int* __restrict__ deg_h,
    int nbg, int nV)
{
    __shared__ float accS[BKV * 33];
    __shared__ float pxS[BKV * 33];
    __shared__ float sW[256];
    __shared__ int degS[BKV];
    int b = blockIdx.x, tid = threadIdx.x;
    bool isG = b < nbg;
    int bucket = isG ? b : b - nbg;
    const int2* slot = isG ? slot_g : slot_h;
    const unsigned* P16 = isG ? PCg16 : PAh16;
    const float* ea = isG ? ea_c : ea_a;
    const float* PX = isG ? PXg : PXh;
    const float* W1 = isG ? gvW1 : hvW1;
    float* Aout = isG ? Ag : Ah;
    int* degout = isG ? deg_g : deg_h;
    int bi = b;   // combined Boff index: [g bins][h bins][a bins]

    int n0 = bucket * BKV;
    int nn = min(BKV, nV - n0);

    for (int i = tid; i < 256; i += 256) sW[i] = W1[(2 * ND + (i >> 5)) * HD + (i & 31)];
    for (int i = tid; i < nn * 32; i += 256) {
        int n = i >> 5, ch = i & 31;
        pxS[n * 33 + ch] = PX[(size_t)(n0 + n) * 32 + ch];
    }
    for (int i = tid; i < BKV * 33; i += 256) accS[i] = 0.f;
    if (tid < BKV) degS[tid] = 0;
    __syncthreads();

    int s0 = Boff[bi], cnt = Bcnt[bi];
    for (int k = tid; k < cnt; k += 256) {
        int2 w = slot[s0 + k];
        int n = w.x & (BKV - 1), src = w.x >> 7, e = w.y;
        const uint4* pr = reinterpret_cast<const uint4*>(P16 + (size_t)src * 16);
        uint4 r0 = pr[0], r1 = pr[1], r2 = pr[2], r3 = pr[3];
        const float4* pe = reinterpret_cast<const float4*>(ea + (size_t)e * ED);
        float4 q0 = pe[0], q1 = pe[1];
        float pc[32], ev[8];
        unpack8(r0, pc); unpack8(r1, pc + 8); unpack8(r2, pc + 16); unpack8(r3, pc + 24);
        ev[0]=q0.x; ev[1]=q0.y; ev[2]=q0.z; ev[3]=q0.w;
        ev[4]=q1.x; ev[5]=q1.y; ev[6]=q1.z; ev[7]=q1.w;
        atomicAdd(&degS[n], 1);
        float* arow = accS + n * 33;
        const float* prow = pxS + n * 33;
#pragma unroll
        for (int ch = 0; ch < 32; ch++) {
            float t = prow[ch] + pc[ch];
#pragma unroll
            for (int i2 = 0; i2 < 8; i2++) t = fmaf(ev[i2], sW[i2 * 32 + ch], t);
            atomicAdd(&arow[ch], fmaxf(t, 0.f));
        }
    }
    __syncthreads();
    for (int i = tid; i < nn * 32; i += 256) {
        int n = i >> 5, ch = i & 31;
        Aout[(size_t)(n0 + n) * 32 + ch] = accS[n * 33 + ch];
    }
    for (int i = tid; i < nn; i += 256) degout[n0 + i] = degS[i];
}

// ===========================================================================
// ga accumulate: one block per 8-node a-bucket.
// ===========================================================================
__global__ __launch_bounds__(256) void gaacc_kernel(
    const int2* __restrict__ slot_a, const unsigned* __restrict__ PFga16,
    const float* __restrict__ ea_a, const float* __restrict__ PXga,
    const float* __restrict__ gaW1,
    const int* __restrict__ Boff, const int* __restrict__ Bcnt, int boffBase,
    float* __restrict__ Aga, int* __restrict__ deg_a, int nA)
{
    __shared__ float accS[BKA * 33];
    __shared__ float pxS[BKA * 33];
    __shared__ float sW[256];
    __shared__ int degS[BKA];
    int b = blockIdx.x, tid = threadIdx.x;
    int n0 = b * BKA;
    int nn = min(BKA, nA - n0);

    for (int i = tid; i < 256; i += 256) sW[i] = gaW1[(ND + HD + (i >> 5)) * HD + (i & 31)];
    for (int i = tid; i < nn * 32; i += 256) {
        int n = i >> 5, ch = i & 31;
        pxS[n * 33 + ch] = PXga[(size_t)(n0 + n) * 32 + ch];
    }
    for (int i = tid; i < BKA * 33; i += 256) accS[i] = 0.f;
    if (tid < BKA) degS[tid] = 0;
    __syncthreads();

    int s0 = Boff[boffBase + b], cnt = Bcnt[boffBase + b];
    for (int k = tid; k < cnt; k += 256) {
        int2 w = slot_a[s0 + k];
        int n = w.x & (BKA - 1), tgt = w.x >> 3, e = w.y;
        const uint4* pr = reinterpret_cast<const uint4*>(PFga16 + (size_t)tgt * 16);
        uint4 r0 = pr[0], r1 = pr[1], r2 = pr[2], r3 = pr[3];
        const float4* pe = reinterpret_cast<const float4*>(ea_a + (size_t)e * ED);
        float4 q0 = pe[0], q1 = pe[1];
        float pf[32], ev[8];
        unpack8(r0, pf); unpack8(r1, pf + 8); unpack8(r2, pf + 16); unpack8(r3, pf + 24);
        ev[0]=q0.x; ev[1]=q0.y; ev[2]=q0.z; ev[3]=q0.w;
        ev[4]=q1.x; ev[5]=q1.y; ev[6]=q1.z; ev[7]=q1.w;
        atomicAdd(&degS[n], 1);
        float* arow = accS + n * 33;
        const float* prow = pxS + n * 33;
#pragma unroll
        for (int ch = 0; ch < 32; ch++) {
            float t = prow[ch] + pf[ch];
#pragma unroll
            for (int i2 = 0; i2 < 8; i2++) t = fmaf(ev[i2], sW[i2 * 32 + ch], t);
            atomicAdd(&arow[ch], fmaxf(t, 0.f));
        }
    }
    __syncthreads();
    for (int i = tid; i < nn * 32; i += 256) {
        int n = i >> 5, ch = i & 31;
        Aga[(size_t)(n0 + n) * 32 + ch] = accS[n * 33 + ch];
    }
    for (int i = tid; i < nn; i += 256) deg_a[n0 + i] = degS[i];
}

// ===========================================================================
// fv node kernel, CHANNEL-PARALLEL: thread = (v, ch).
// ===========================================================================
__global__ __launch_bounds__(256) void fv_node_kernel(
    const float* __restrict__ xv,
    const float* __restrict__ Ag, const float* __restrict__ Ah,
    const int* __restrict__ deg_g, const int* __restrict__ deg_h,
    const float* __restrict__ fvW1, const float* __restrict__ fvb1,
    const float* __restrict__ Mg, const float* __restrict__ bg,
    const float* __restrict__ Mh, const float* __restrict__ bh,
    const float* __restrict__ Nfv, const float* __restrict__ bfv,
    unsigned* __restrict__ PFga16, int nV)
{
    __shared__ float sMg[1024], sMh[1024], sN[1024], sF[512];
    __shared__ float sbg[32], sbh[32], sbf[32], sb1[32];
    for (int i = threadIdx.x; i < 1024; i += 256) {
        sMg[i] = Mg[i]; sMh[i] = Mh[i]; sN[i] = Nfv[i];
    }
    for (int i = threadIdx.x; i < 512; i += 256) sF[i] = fvW1[i];
    if (threadIdx.x < 32) {
        sbg[threadIdx.x] = bg[threadIdx.x];
        sbh[threadIdx.x] = bh[threadIdx.x];
        sbf[threadIdx.x] = bfv[threadIdx.x];
        sb1[threadIdx.x] = fvb1[threadIdx.x];
    }
    __syncthreads();

    int gid = blockIdx.x * 256 + threadIdx.x;
    int v = gid >> 5, ch = threadIdx.x & 31;
    if (v >= nV) return;

    float x = (ch < ND) ? xv[(size_t)v * ND + ch] : 0.f;
    float t = sb1[ch];
#pragma unroll
    for (int i = 0; i < ND; i++) t = fmaf(__shfl(x, i, 32), sF[i * 32 + ch], t);

    float agr[HD], ahr[HD];
    {
        const float4* pg4 = reinterpret_cast<const float4*>(Ag + (size_t)v * HD);
        const float4* ph4 = reinterpret_cast<const float4*>(Ah + (size_t)v * HD);
#pragma unroll
        for (int q = 0; q < 8; q++) {
            float4 a = pg4[q];
            agr[4*q+0] = a.x; agr[4*q+1] = a.y; agr[4*q+2] = a.z; agr[4*q+3] = a.w;
            float4 b = ph4[q];
            ahr[4*q+0] = b.x; ahr[4*q+1] = b.y; ahr[4*q+2] = b.z; ahr[4*q+3] = b.w;
        }
    }
    float sg = 0.f, sh = 0.f;
#pragma unroll
    for (int c = 0; c < HD; c++) {
        sg = fmaf(agr[c], sMg[c * 32 + ch], sg);
        sh = fmaf(ahr[c], sMh[c * 32 + ch], sh);
    }
    int dg = deg_g[v], dh = deg_h[v];
    float invg = dg > 0 ? 1.f / (float)dg : 0.f;
    float invh = dh > 0 ? 1.f / (float)dh : 0.f;
    t += (dg > 0 ? sbg[ch] : 0.f) + (dh > 0 ? sbh[ch] : 0.f) + invg * sg + invh * sh;
    float hid = fmaxf(t, 0.f);

    float pf = sbf[ch];
#pragma unroll
    for (int h = 0; h < HD; h++) pf = fmaf(__shfl(hid, h, 32), sN[h * 32 + ch], pf);
    float hi = __shfl_xor(pf, 1, 32);
    if (!(ch & 1)) PFga16[(size_t)v * 16 + (ch >> 1)] = packbf2(pf, hi);
}

// ===========================================================================
// fa node kernel, CHANNEL-PARALLEL: thread = (a, ch) -> final output.
// ===========================================================================
__global__ __launch_bounds__(256) void fa_node_kernel(
    const float* __restrict__ xa,
    const float* __restrict__ Aga, const int* __restrict__ deg_a,
    const float* __restrict__ faW1, const float* __restrict__ fab1,
    const float* __restrict__ faW2, const float* __restrict__ fab2,
    const float* __restrict__ Mga, const float* __restrict__ bga,
    float* __restrict__ out, int nA)
{
    __shared__ float sM[1024], sW2[1024], sF[512];
    __shared__ float sbga[32], sb1[32], sb2[32];
    for (int i = threadIdx.x; i < 1024; i += 256) { sM[i] = Mga[i]; sW2[i] = faW2[i]; }
    for (int i = threadIdx.x; i < 512; i += 256) sF[i] = faW1[i];
    if (threadIdx.x < 32) {
        sbga[threadIdx.x] = bga[threadIdx.x];
        sb1[threadIdx.x]  = fab1[threadIdx.x];
        sb2[threadIdx.x]  = fab2[threadIdx.x];
    }
    __syncthreads();

    int gid = blockIdx.x * 256 + threadIdx.x;
    int a = gid >> 5, ch = threadIdx.x & 31;
    if (a >= nA) return;

    float x = (ch < ND) ? xa[(size_t)a * ND + ch] : 0.f;
    float t = sb1[ch];
#pragma unroll
    for (int i = 0; i < ND; i++) t = fmaf(__shfl(x, i, 32), sF[i * 32 + ch], t);

    float agr[HD];
    {
        const float4* pg4 = reinterpret_cast<const float4*>(Aga + (size_t)a * HD);
#pragma unroll
        for (int q = 0; q < 8; q++) {
            float4 w = pg4[q];
            agr[4*q+0] = w.x; agr[4*q+1] = w.y; agr[4*q+2] = w.z; agr[4*q+3] = w.w;
        }
    }
    float s = 0.f;
#pragma unroll
    for (int c = 0; c < HD; c++) s = fmaf(agr[c], sM[c * 32 + ch], s);
    int d = deg_a[a];
    float inv = d > 0 ? 1.f / (float)d : 0.f;
    t += (d > 0 ? sbga[ch] : 0.f) + inv * s;
    float hid = fmaxf(t, 0.f);

    float o = sb2[ch];
#pragma unroll
    for (int h = 0; h < HD; h++) o = fmaf(__shfl(hid, h, 32), sW2[h * 32 + ch], o);
    out[(size_t)a * HD + ch] = o;
}

// ===========================================================================
extern "C" void kernel_launch(void* const* d_in, const int* in_sizes, int n_in,
                              void* d_out, int out_size, void* d_ws, size_t ws_size,
                              hipStream_t stream) {
    const float* x_c    = (const float*)d_in[0];
    const float* x_v    = (const float*)d_in[1];
    const float* x_a    = (const float*)d_in[2];
    const int*   ei_c2v = (const int*)d_in[3];
    const int*   ei_a2v = (const int*)d_in[4];
    const float* ea_c2v = (const float*)d_in[5];
    const float* ea_a2v = (const float*)d_in[6];
    const float *gv_W1=(const float*)d_in[7],  *gv_b1=(const float*)d_in[8],
                *gv_W2=(const float*)d_in[9],  *gv_b2=(const float*)d_in[10];
    const float *hv_W1=(const float*)d_in[11], *hv_b1=(const float*)d_in[12],
                *hv_W2=(const float*)d_in[13], *hv_b2=(const float*)d_in[14];
    const float *fv_W1=(const float*)d_in[15], *fv_b1=(const float*)d_in[16],
                *fv_W2=(const float*)d_in[17], *fv_b2=(const float*)d_in[18];
    const float *ga_W1=(const float*)d_in[19], *ga_b1=(const float*)d_in[20],
                *ga_W2=(const float*)d_in[21], *ga_b2=(const float*)d_in[22];
    const float *fa_W1=(const float*)d_in[23], *fa_b1=(const float*)d_in[24],
                *fa_W2=(const float*)d_in[25], *fa_b2=(const float*)d_in[26];

    const int NC = in_sizes[0] / ND;
    const int NV = in_sizes[1] / ND;
    const int NA = in_sizes[2] / ND;
    const int EC = in_sizes[3] / 2;
    const int EA = in_sizes[4] / 2;
    (void)n_in; (void)out_size; (void)ws_size;

    const int* c2v_s = ei_c2v;            // constraint side of c2v
    const int* c2v_t = ei_c2v + EC;       // variable side
    const int* a2v_s = ei_a2v;            // cut node side
    const int* a2v_t = ei_a2v + EA;       // variable side

    const int nbg = (NV + BKV - 1) / BKV;   // <= 1024 (NV <= 131072)
    const int nbh = nbg;
    const int nba = (NA + BKA - 1) / BKA;   // <= 1024 (NA <= 8192)
    const int nb  = nbg + nbh + nba;

    // Workspace layout (4B words)
    int* wsI = (int*)d_ws;
    int* deg_g = wsI;                 // NV
    int* deg_h = deg_g + NV;          // NV
    int* deg_a = deg_h + NV;          // NA
    int* Bcnt  = deg_a + NA;          // nb
    int* Boff  = Bcnt + nb;           // nb
    int* cntg  = Boff + nb;                      // NCHK*nbg
    int* cnth  = cntg + (size_t)NCHK * nbg;      // NCHK*nbh
    int* cnta  = cnth + (size_t)NCHK * nbh;      // NCHK*nba
    int* endcnt = cnta + (size_t)NCHK * nba;
    size_t words = (size_t)(endcnt - wsI);
    if (words & 1) words++;                      // 8B-align slots
    int2* slot_g = (int2*)(wsI + words);    // EC
    int2* slot_h = slot_g + EC;             // EA
    int2* slot_a = slot_h + EA;             // EA
    float* PXg = (float*)(slot_a + EA);     // NV*32 (aliased as PFga16 later)
    float* PXh = PXg + (size_t)NV * HD;     // NV*32
    float* PXga= PXh + (size_t)NV * HD;     // NA*32
    float* Ag  = PXga + (size_t)NA * HD;    // NV*32
    float* Ah  = Ag + (size_t)NV * HD;      // NV*32
    float* Aga = Ah + (size_t)NV * HD;      // NA*32
    unsigned* PCg16 = (unsigned*)(Aga + (size_t)NA * HD);  // NC*16
    unsigned* PAh16 = PCg16 + (size_t)NC * 16;             // NA*16
    float* Mg  = (float*)(PAh16 + (size_t)NA * 16);        // 1024
    float* Mh  = Mg + HD * HD;            // 1024
    float* Mga = Mh + HD * HD;            // 1024
    float* Nfv = Mga + HD * HD;           // 1024
    float* bgv = Nfv + HD * HD;           // 32
    float* bhv = bgv + HD;                // 32
    float* bgav= bhv + HD;                // 32
    float* bfv = bgav + HD;               // 32
    unsigned* PFga16 = (unsigned*)PXg;    // alias: PXg dead after fvacc

    // standalone precompute (independent of sort)
    {
        int bV = (NV * 32 + 255) / 256, bC = (NC * 32 + 255) / 256, bA = (NA * 32 + 255) / 256;
        precompC_kernel<<<bV + bC + bA + 4, 256, 0, stream>>>(
            x_v, x_c, x_a,
            gv_W1, gv_b1, hv_W1, hv_b1, ga_W1, ga_b1,
            gv_W2, gv_b2, hv_W2, hv_b2, ga_W2, ga_b2,
            fv_W1, fv_W2, fv_b2, fa_W1,
            PXg, PXh, PXga, PCg16, PAh16,
            Mg, bgv, Mh, bhv, Mga, bgav, Nfv, bfv, NV, NC, NA);
    }

    // bucket histogram (stream read once; small LDS bins)
    countB_kernel<<<2 * NCHK, 256, 0, stream>>>(
        c2v_t, cntg, EC, a2v_t, a2v_s, cnth, cnta, EA, nbg, nbh, nba);

    // bucket totals -> offsets -> per-(chunk,bucket) bases
    bsum_kernel<<<(nb + 255) / 256, 256, 0, stream>>>(
        cntg, cnth, cnta, Bcnt, Boff, nbg, nbh, nba);
    bscan_kernel<<<3, 1024, 0, stream>>>(Boff, nbg, nbh, nba);
    bbase_kernel<<<(nb + 255) / 256, 256, 0, stream>>>(
        cntg, cnth, cnta, Boff, nbg, nbh, nba);

    // bucket scatter (contiguous runs per block-bucket)
    scatterBk_kernel<<<2 * NCHK, 256, 0, stream>>>(
        c2v_t, c2v_s, cntg, slot_g, EC,
        a2v_t, a2v_s, cnth, cnta, slot_h, slot_a, EA, nbg, nbh, nba);

    // fv edge accumulation: one block per bucket (g then h), LDS acc
    fvacc_kernel<<<nbg + nbh, 256, 0, stream>>>(
        slot_g, slot_h, PCg16, PAh16, ea_c2v, ea_a2v,
        PXg, PXh, gv_W1, hv_W1, Boff, Bcnt,
        Ag, Ah, deg_g, deg_h, nbg, NV);

    // variable-node MLP -> PFga16
    fv_node_kernel<<<(NV * 32 + 255) / 256, 256, 0, stream>>>(
        x_v, Ag, Ah, deg_g, deg_h,
        fv_W1, fv_b1, Mg, bgv, Mh, bhv, Nfv, bfv, PFga16, NV);

    // ga edge accumulation: one block per 8-node a-bucket
    gaacc_kernel<<<nba, 256, 0, stream>>>(
        slot_a, PFga16, ea_a2v, PXga, ga_W1,
        Boff, Bcnt, nbg + nbh, Aga, deg_a, NA);

    // cut-node MLP -> output
    fa_node_kernel<<<(NA * 32 + 255) / 256, 256, 0, stream>>>(
        x_a, Aga, deg_a,
        fa_W1, fa_b1, fa_W2, fa_b2, Mga, bgav, (float*)d_out, NA);
}

// Round 13
// 349.377 us; speedup vs baseline: 2.4895x; 2.4895x over previous
//
#include <hip/hip_runtime.h>

#define HD 32    // hidden/emb dim
#define ND 16    // node feature dim
#define ED 8     // edge feature dim
#define NCHK 256 // edge-stream chunks per list
#define MAXLB 2048  // max histogram bins in LDS
#define BKV 128  // v-nodes per bucket (shift 7)
#define BKA 8    // a-nodes per bucket (shift 3)

// ---------------- bf16 pack/unpack helpers ----------------
__device__ __forceinline__ unsigned bf16rne(float f) {
    unsigned u = __float_as_uint(f);
    return (u + 0x7fffu + ((u >> 16) & 1u)) >> 16;
}
__device__ __forceinline__ unsigned packbf2(float lo, float hi) {
    return bf16rne(lo) | (bf16rne(hi) << 16);
}
__device__ __forceinline__ void unpack8(uint4 r, float* p) {
    p[0] = __uint_as_float(r.x << 16); p[1] = __uint_as_float(r.x & 0xffff0000u);
    p[2] = __uint_as_float(r.y << 16); p[3] = __uint_as_float(r.y & 0xffff0000u);
    p[4] = __uint_as_float(r.z << 16); p[5] = __uint_as_float(r.z & 0xffff0000u);
    p[6] = __uint_as_float(r.w << 16); p[7] = __uint_as_float(r.w & 0xffff0000u);
}

// ===========================================================================
// Standalone channel-parallel precompute (unchanged from round 11).
// ===========================================================================
__global__ __launch_bounds__(256) void precompC_kernel(
    const float* __restrict__ xv, const float* __restrict__ xc, const float* __restrict__ xa,
    const float* __restrict__ gvW1, const float* __restrict__ gvb1,
    const float* __restrict__ hvW1, const float* __restrict__ hvb1,
    const float* __restrict__ gaW1, const float* __restrict__ gab1,
    const float* __restrict__ gvW2, const float* __restrict__ gvb2,
    const float* __restrict__ hvW2, const float* __restrict__ hvb2,
    const float* __restrict__ gaW2, const float* __restrict__ gab2,
    const float* __restrict__ fvW1, const float* __restrict__ fvW2,
    const float* __restrict__ fvb2, const float* __restrict__ faW1,
    float* __restrict__ PXg, float* __restrict__ PXh, float* __restrict__ PXga,
    unsigned* __restrict__ PCg16, unsigned* __restrict__ PAh16,
    float* __restrict__ Mg, float* __restrict__ bg,
    float* __restrict__ Mh, float* __restrict__ bh,
    float* __restrict__ Mga, float* __restrict__ bga,
    float* __restrict__ Nfv, float* __restrict__ bfv,
    int nV, int nC, int nA)
{
    int bV = (nV * 32 + 255) / 256, bC = (nC * 32 + 255) / 256, bA = (nA * 32 + 255) / 256;
    int b = blockIdx.x;
    int tid = threadIdx.x;
    int ch = tid & 31;
    __shared__ float s0[512], s1[512];

    if (b < bV) {
        for (int i = tid; i < 512; i += 256) { s0[i] = gvW1[i]; s1[i] = hvW1[i]; }
        __syncthreads();
        int v = (b * 256 + tid) >> 5;
        if (v >= nV) return;
        float x = (ch < ND) ? xv[(size_t)v * ND + ch] : 0.f;
        float pg = gvb1[ch], ph = hvb1[ch];
#pragma unroll
        for (int i = 0; i < ND; i++) {
            float xi = __shfl(x, i, 32);
            pg = fmaf(xi, s0[i * 32 + ch], pg);
            ph = fmaf(xi, s1[i * 32 + ch], ph);
        }
        PXg[(size_t)v * 32 + ch] = pg;
        PXh[(size_t)v * 32 + ch] = ph;
    } else if (b < bV + bC) {
        for (int i = tid; i < 512; i += 256) s0[i] = gvW1[512 + i];
        __syncthreads();
        int c = ((b - bV) * 256 + tid) >> 5;
        if (c >= nC) return;
        float x = (ch < ND) ? xc[(size_t)c * ND + ch] : 0.f;
        float p = 0.f;
#pragma unroll
        for (int i = 0; i < ND; i++) p = fmaf(__shfl(x, i, 32), s0[i * 32 + ch], p);
        float hi = __shfl_xor(p, 1, 32);
        if (!(ch & 1)) PCg16[(size_t)c * 16 + (ch >> 1)] = packbf2(p, hi);
    } else if (b < bV + bC + bA) {
        for (int i = tid; i < 512; i += 256) { s0[i] = hvW1[512 + i]; s1[i] = gaW1[i]; }
        __syncthreads();
        int a = ((b - bV - bC) * 256 + tid) >> 5;
        if (a >= nA) return;
        float x = (ch < ND) ? xa[(size_t)a * ND + ch] : 0.f;
        float ph = 0.f, pg = gab1[ch];
#pragma unroll
        for (int i = 0; i < ND; i++) {
            float xi = __shfl(x, i, 32);
            ph = fmaf(xi, s0[i * 32 + ch], ph);
            pg = fmaf(xi, s1[i * 32 + ch], pg);
        }
        float hi = __shfl_xor(ph, 1, 32);
        if (!(ch & 1)) PAh16[(size_t)a * 16 + (ch >> 1)] = packbf2(ph, hi);
        PXga[(size_t)a * 32 + ch] = pg;
    } else {
        int m = b - (bV + bC + bA);
        const float *W2, *b2, *T; float *M, *bb; int toff;
        if (m == 0)      { W2 = gvW2; b2 = gvb2; T = fvW1; toff = ND;      M = Mg;  bb = bg;  }
        else if (m == 1) { W2 = hvW2; b2 = hvb2; T = fvW1; toff = ND + HD; M = Mh;  bb = bh;  }
        else if (m == 2) { W2 = gaW2; b2 = gab2; T = faW1; toff = ND;      M = Mga; bb = bga; }
        else             { W2 = fvW2; b2 = fvb2; T = gaW1; toff = ND;      M = Nfv; bb = bfv; }
        for (int idx = tid; idx < 1024; idx += 256) {
            int c = idx >> 5, h = idx & 31;
            float s = 0.f;
#pragma unroll
            for (int o = 0; o < HD; o++) s = fmaf(W2[c * HD + o], T[(toff + o) * HD + h], s);
            M[idx] = s;
        }
        if (tid < HD) {
            int h = tid;
            float s = 0.f;
#pragma unroll
            for (int o = 0; o < HD; o++) s = fmaf(b2[o], T[(toff + o) * HD + h], s);
            bb[h] = s;
        }
    }
}

// ===========================================================================
// Bucket histogram (streams read once; small LDS bins).
// ===========================================================================
__global__ __launch_bounds__(256) void countB_kernel(
    const int* __restrict__ c2v_t, int* __restrict__ cntg, int nEC,
    const int* __restrict__ a2v_t, const int* __restrict__ a2v_s,
    int* __restrict__ cnth, int* __restrict__ cnta, int nEA,
    int nbg, int nbh, int nba)
{
    __shared__ int lcnt[MAXLB];
    int b = blockIdx.x, tid = threadIdx.x;
    if (b < NCHK) {
        int chunk = b;
        for (int i = tid; i < nbg; i += 256) lcnt[i] = 0;
        __syncthreads();
        int CH = ((nEC + NCHK - 1) / NCHK + 255) & ~255;
        int i0 = chunk * CH, i1 = min(i0 + CH, nEC);
        for (int i = i0 + tid; i < i1; i += 256)
            atomicAdd(&lcnt[c2v_t[i] >> 7], 1);
        __syncthreads();
        int* out = cntg + (size_t)chunk * nbg;
        for (int i = tid; i < nbg; i += 256) out[i] = lcnt[i];
    } else {
        int chunk = b - NCHK;
        for (int i = tid; i < nbh + nba; i += 256) lcnt[i] = 0;
        __syncthreads();
        int CH = ((nEA + NCHK - 1) / NCHK + 255) & ~255;
        int i0 = chunk * CH, i1 = min(i0 + CH, nEA);
        for (int i = i0 + tid; i < i1; i += 256) {
            atomicAdd(&lcnt[a2v_t[i] >> 7], 1);
            atomicAdd(&lcnt[nbh + (a2v_s[i] >> 3)], 1);
        }
        __syncthreads();
        int* outh = cnth + (size_t)chunk * nbh;
        for (int i = tid; i < nbh; i += 256) outh[i] = lcnt[i];
        int* outa = cnta + (size_t)chunk * nba;
        for (int i = tid; i < nba; i += 256) outa[i] = lcnt[nbh + i];
    }
}

// Bcnt[b] = sum over chunks; Boff initialized same (scanned in place next).
__global__ __launch_bounds__(256) void bsum_kernel(
    const int* __restrict__ cntg, const int* __restrict__ cnth, const int* __restrict__ cnta,
    int* __restrict__ Bcnt, int* __restrict__ Boff, int nbg, int nbh, int nba)
{
    int i = blockIdx.x * 256 + threadIdx.x;
    int nb = nbg + nbh + nba;
    if (i >= nb) return;
    const int* cnt; int bin, stride;
    if (i < nbg)            { cnt = cntg; bin = i;             stride = nbg; }
    else if (i < nbg + nbh) { cnt = cnth; bin = i - nbg;       stride = nbh; }
    else                    { cnt = cnta; bin = i - nbg - nbh; stride = nba; }
    int s = 0;
    for (int c = 0; c < NCHK; c++) s += cnt[(size_t)c * stride + bin];
    Bcnt[i] = s; Boff[i] = s;
}

__device__ __forceinline__ void exscan_block(int* __restrict__ c, int n)
{
    int i = threadIdx.x;
    int v = (i < n) ? c[i] : 0;
    int x = v;
    int lane = i & 63, wid = i >> 6;
#pragma unroll
    for (int dd = 1; dd < 64; dd <<= 1) {
        int y = __shfl_up(x, dd, 64);
        if (lane >= dd) x += y;
    }
    __shared__ int ws[16];
    if (lane == 63) ws[wid] = x;
    __syncthreads();
    if (i == 0) {
        int a = 0;
#pragma unroll
        for (int w = 0; w < 16; w++) { int t = ws[w]; ws[w] = a; a += t; }
    }
    __syncthreads();
    int excl = ws[wid] + x - v;
    if (i < n) c[i] = excl;
}

__global__ __launch_bounds__(1024) void bscan_kernel(
    int* __restrict__ Boff, int nbg, int nbh, int nba)
{
    if (blockIdx.x == 0)      exscan_block(Boff, nbg);
    else if (blockIdx.x == 1) exscan_block(Boff + nbg, nbh);
    else                      exscan_block(Boff + nbg + nbh, nba);
}

// cnt[c][bin] <- Boff[bin] + prefix over chunks
__global__ __launch_bounds__(256) void bbase_kernel(
    int* __restrict__ cntg, int* __restrict__ cnth, int* __restrict__ cnta,
    const int* __restrict__ Boff, int nbg, int nbh, int nba)
{
    int i = blockIdx.x * 256 + threadIdx.x;
    int nb = nbg + nbh + nba;
    if (i >= nb) return;
    int* cnt; int bin, stride;
    if (i < nbg)            { cnt = cntg; bin = i;             stride = nbg; }
    else if (i < nbg + nbh) { cnt = cnth; bin = i - nbg;       stride = nbh; }
    else                    { cnt = cnta; bin = i - nbg - nbh; stride = nba; }
    int running = Boff[i];
    for (int c = 0; c < NCHK; c++) {
        int t = cnt[(size_t)c * stride + bin];
        cnt[(size_t)c * stride + bin] = running;
        running += t;
    }
}

// ===========================================================================
// Bucket scatter: slot = {packed_ids, eid}, per-(chunk,bucket) runs
// contiguous -> ~1x write amp. g/h: packed=(src<<7)|(t&127); a: (tgt<<3)|(s&7)
// ===========================================================================
__global__ __launch_bounds__(256) void scatterBk_kernel(
    const int* __restrict__ c2v_t, const int* __restrict__ c2v_s,
    const int* __restrict__ cntg, int2* __restrict__ slot_g, int nEC,
    const int* __restrict__ a2v_t, const int* __restrict__ a2v_s,
    const int* __restrict__ cnth, const int* __restrict__ cnta,
    int2* __restrict__ slot_h, int2* __restrict__ slot_a, int nEA,
    int nbg, int nbh, int nba)
{
    __shared__ int lbase[MAXLB];
    int b = blockIdx.x, tid = threadIdx.x;
    if (b < NCHK) {
        int chunk = b;
        const int* src = cntg + (size_t)chunk * nbg;
        for (int i = tid; i < nbg; i += 256) lbase[i] = src[i];
        __syncthreads();
        int CH = ((nEC + NCHK - 1) / NCHK + 255) & ~255;
        int i0 = chunk * CH, i1 = min(i0 + CH, nEC);
        for (int i = i0 + tid; i < i1; i += 256) {
            int t = c2v_t[i], s = c2v_s[i];
            int p = atomicAdd(&lbase[t >> 7], 1);
            slot_g[p] = make_int2((s << 7) | (t & 127), i);
        }
    } else {
        int chunk = b - NCHK;
        const int* srch = cnth + (size_t)chunk * nbh;
        for (int i = tid; i < nbh; i += 256) lbase[i] = srch[i];
        const int* srca = cnta + (size_t)chunk * nba;
        for (int i = tid; i < nba; i += 256) lbase[nbh + i] = srca[i];
        __syncthreads();
        int CH = ((nEA + NCHK - 1) / NCHK + 255) & ~255;
        int i0 = chunk * CH, i1 = min(i0 + CH, nEA);
        for (int i = i0 + tid; i < i1; i += 256) {
            int t = a2v_t[i], s = a2v_s[i];
            int p = atomicAdd(&lbase[t >> 7], 1);
            slot_h[p] = make_int2((s << 7) | (t & 127), i);
            int q = atomicAdd(&lbase[nbh + (s >> 3)], 1);
            slot_a[q] = make_int2((t << 3) | (s & 7), i);
        }
    }
}

// ===========================================================================
// In-bucket counting sort: node-granular order within each bucket.
// Two passes over the bucket's slots (global); LDS bins only. Emits
// per-node deg and GLOBAL slot offsets (within-list), plus sorted slots.
// ===========================================================================
__global__ __launch_bounds__(256) void bsort_kernel(
    const int2* __restrict__ slotU_g, const int2* __restrict__ slotU_h,
    const int2* __restrict__ slotU_a,
    int2* __restrict__ slotS_g, int2* __restrict__ slotS_h,
    int2* __restrict__ slotS_a,
    const int* __restrict__ Boff, const int* __restrict__ Bcnt,
    int* __restrict__ deg_g, int* __restrict__ deg_h, int* __restrict__ deg_a,
    int* __restrict__ off_g, int* __restrict__ off_h, int* __restrict__ off_a,
    int nbg, int nbh, int nba, int nV, int nA)
{
    __shared__ int bins[BKV];
    __shared__ int binoff[BKV];
    int b = blockIdx.x, tid = threadIdx.x;
    const int2* in; int2* out; int nbins; int* deg; int* off; int n0, nn;
    if (b < nbg) {
        in = slotU_g; out = slotS_g; nbins = BKV; deg = deg_g; off = off_g;
        n0 = b * BKV; nn = min(BKV, nV - n0);
    } else if (b < nbg + nbh) {
        in = slotU_h; out = slotS_h; nbins = BKV; deg = deg_h; off = off_h;
        n0 = (b - nbg) * BKV; nn = min(BKV, nV - n0);
    } else {
        in = slotU_a; out = slotS_a; nbins = BKA; deg = deg_a; off = off_a;
        n0 = (b - nbg - nbh) * BKA; nn = min(BKA, nA - n0);
    }
    int mask = nbins - 1;
    int s0 = Boff[b], cnt = Bcnt[b];

    for (int i = tid; i < nbins; i += 256) bins[i] = 0;
    __syncthreads();
    for (int k = tid; k < cnt; k += 256)
        atomicAdd(&bins[in[s0 + k].x & mask], 1);
    __syncthreads();
    if (tid == 0) {
        int run = 0;
        for (int i = 0; i < nbins; i++) { binoff[i] = run; run += bins[i]; }
    }
    __syncthreads();
    for (int i = tid; i < nn; i += 256) {
        deg[n0 + i] = bins[i];
        off[n0 + i] = s0 + binoff[i];
    }
    for (int i = tid; i < nbins; i += 256) bins[i] = binoff[i];
    __syncthreads();
    for (int k = tid; k < cnt; k += 256) {
        int2 w = in[s0 + k];
        int p = atomicAdd(&bins[w.x & mask], 1);
        out[s0 + p] = w;
    }
}

// ===========================================================================
// fv edge kernel (round-11 structure): 8 lanes per variable node.
// slot = {(src<<7)|n, eid}; gather ea via eid; bf16 partial row via src.
// ===========================================================================
__global__ __launch_bounds__(256) void fv_edge_kernel(
    const float* __restrict__ PXg, const unsigned* __restrict__ PCg16,
    const float* __restrict__ PXh, const unsigned* __restrict__ PAh16,
    const int2* __restrict__ slot_g, const int2* __restrict__ slot_h,
    const float* __restrict__ ea_c, const float* __restrict__ ea_a,
    const int* __restrict__ off_g, const int* __restrict__ deg_g,
    const int* __restrict__ off_h, const int* __restrict__ deg_h,
    const float* __restrict__ gvW1, const float* __restrict__ hvW1,
    float* __restrict__ Ag, float* __restrict__ Ah, int nV)
{
    int gid = blockIdx.x * 256 + threadIdx.x;
    int v   = gid >> 3;
    int sub = threadIdx.x & 7;
    if (v >= nV) return;

    float px[HD], acc[HD];

    // ---------------- g: c2v edges ----------------
    {
        const float4* pp = reinterpret_cast<const float4*>(PXg + (size_t)v * HD);
#pragma unroll
        for (int q = 0; q < 8; q++) {
            float4 t = pp[q];
            px[4*q+0] = t.x; px[4*q+1] = t.y; px[4*q+2] = t.z; px[4*q+3] = t.w;
        }
#pragma unroll
        for (int ch = 0; ch < HD; ch++) acc[ch] = 0.f;

        int base = off_g[v], d = deg_g[v];
        for (int k = sub; k < d; k += 8) {
            int2 w = slot_g[base + k];
            int s = w.x >> 7, e = w.y;
            const uint4* pr = reinterpret_cast<const uint4*>(PCg16 + (size_t)s * 16);
            uint4 r0 = pr[0], r1 = pr[1], r2 = pr[2], r3 = pr[3];
            const float4* pe = reinterpret_cast<const float4*>(ea_c + (size_t)e * ED);
            float4 q0 = pe[0], q1 = pe[1];
            float pc[HD], ev[ED];
            unpack8(r0, pc + 0); unpack8(r1, pc + 8);
            unpack8(r2, pc + 16); unpack8(r3, pc + 24);
            ev[0]=q0.x; ev[1]=q0.y; ev[2]=q0.z; ev[3]=q0.w;
            ev[4]=q1.x; ev[5]=q1.y; ev[6]=q1.z; ev[7]=q1.w;
#pragma unroll
            for (int ch = 0; ch < HD; ch++) {
                float t = px[ch] + pc[ch];
#pragma unroll
                for (int i = 0; i < ED; i++) t = fmaf(ev[i], gvW1[(2 * ND + i) * HD + ch], t);
                acc[ch] += fmaxf(t, 0.f);
            }
        }
#pragma unroll
        for (int m = 1; m < 8; m <<= 1) {
#pragma unroll
            for (int ch = 0; ch < HD; ch++) acc[ch] += __shfl_xor(acc[ch], m, 64);
        }
        if (sub == 0) {
            float4* dst = reinterpret_cast<float4*>(Ag + (size_t)v * HD);
#pragma unroll
            for (int q = 0; q < 8; q++)
                dst[q] = make_float4(acc[4*q+0], acc[4*q+1], acc[4*q+2], acc[4*q+3]);
        }
    }

    // ---------------- h: a2v edges ----------------
    {
        const float4* pp = reinterpret_cast<const float4*>(PXh + (size_t)v * HD);
#pragma unroll
        for (int q = 0; q < 8; q++) {
            float4 t = pp[q];
            px[4*q+0] = t.x; px[4*q+1] = t.y; px[4*q+2] = t.z; px[4*q+3] = t.w;
        }
#pragma unroll
        for (int ch = 0; ch < HD; ch++) acc[ch] = 0.f;

        int base = off_h[v], d = deg_h[v];
        for (int k = sub; k < d; k += 8) {
            int2 w = slot_h[base + k];
            int s = w.x >> 7, e = w.y;
            const uint4* pr = reinterpret_cast<const uint4*>(PAh16 + (size_t)s * 16);
            uint4 r0 = pr[0], r1 = pr[1], r2 = pr[2], r3 = pr[3];
            const float4* pe = reinterpret_cast<const float4*>(ea_a + (size_t)e * ED);
            float4 q0 = pe[0], q1 = pe[1];
            float pc[HD], ev[ED];
            unpack8(r0, pc + 0); unpack8(r1, pc + 8);
            unpack8(r2, pc + 16); unpack8(r3, pc + 24);
            ev[0]=q0.x; ev[1]=q0.y; ev[2]=q0.z; ev[3]=q0.w;
            ev[4]=q1.x; ev[5]=q1.y; ev[6]=q1.z; ev[7]=q1.w;
#pragma unroll
            for (int ch = 0; ch < HD; ch++) {
                float t = px[ch] + pc[ch];
#pragma unroll
                for (int i = 0; i < ED; i++) t = fmaf(ev[i], hvW1[(2 * ND + i) * HD + ch], t);
                acc[ch] += fmaxf(t, 0.f);
            }
        }
#pragma unroll
        for (int m = 1; m < 8; m <<= 1) {
#pragma unroll
            for (int ch = 0; ch < HD; ch++) acc[ch] += __shfl_xor(acc[ch], m, 64);
        }
        if (sub == 0) {
            float4* dst = reinterpret_cast<float4*>(Ah + (size_t)v * HD);
#pragma unroll
            for (int q = 0; q < 8; q++)
                dst[q] = make_float4(acc[4*q+0], acc[4*q+1], acc[4*q+2], acc[4*q+3]);
        }
    }
}

// ===========================================================================
// fv node kernel, CHANNEL-PARALLEL (unchanged from round 11).
// ===========================================================================
__global__ __launch_bounds__(256) void fv_node_kernel(
    const float* __restrict__ xv,
    const float* __restrict__ Ag, const float* __restrict__ Ah,
    const int* __restrict__ deg_g, const int* __restrict__ deg_h,
    const float* __restrict__ fvW1, const float* __restrict__ fvb1,
    const float* __restrict__ Mg, const float* __restrict__ bg,
    const float* __restrict__ Mh, const float* __restrict__ bh,
    const float* __restrict__ Nfv, const float* __restrict__ bfv,
    unsigned* __restrict__ PFga16, int nV)
{
    __shared__ float sMg[1024], sMh[1024], sN[1024], sF[512];
    __shared__ float sbg[32], sbh[32], sbf[32], sb1[32];
    for (int i = threadIdx.x; i < 1024; i += 256) {
        sMg[i] = Mg[i]; sMh[i] = Mh[i]; sN[i] = Nfv[i];
    }
    for (int i = threadIdx.x; i < 512; i += 256) sF[i] = fvW1[i];
    if (threadIdx.x < 32) {
        sbg[threadIdx.x] = bg[threadIdx.x];
        sbh[threadIdx.x] = bh[threadIdx.x];
        sbf[threadIdx.x] = bfv[threadIdx.x];
        sb1[threadIdx.x] = fvb1[threadIdx.x];
    }
    __syncthreads();

    int gid = blockIdx.x * 256 + threadIdx.x;
    int v = gid >> 5, ch = threadIdx.x & 31;
    if (v >= nV) return;

    float x = (ch < ND) ? xv[(size_t)v * ND + ch] : 0.f;
    float t = sb1[ch];
#pragma unroll
    for (int i = 0; i < ND; i++) t = fmaf(__shfl(x, i, 32), sF[i * 32 + ch], t);

    float agr[HD], ahr[HD];
    {
        const float4* pg4 = reinterpret_cast<const float4*>(Ag + (size_t)v * HD);
        const float4* ph4 = reinterpret_cast<const float4*>(Ah + (size_t)v * HD);
#pragma unroll
        for (int q = 0; q < 8; q++) {
            float4 a = pg4[q];
            agr[4*q+0] = a.x; agr[4*q+1] = a.y; agr[4*q+2] = a.z; agr[4*q+3] = a.w;
            float4 b = ph4[q];
            ahr[4*q+0] = b.x; ahr[4*q+1] = b.y; ahr[4*q+2] = b.z; ahr[4*q+3] = b.w;
        }
    }
    float sg = 0.f, sh = 0.f;
#pragma unroll
    for (int c = 0; c < HD; c++) {
        sg = fmaf(agr[c], sMg[c * 32 + ch], sg);
        sh = fmaf(ahr[c], sMh[c * 32 + ch], sh);
    }
    int dg = deg_g[v], dh = deg_h[v];
    float invg = dg > 0 ? 1.f / (float)dg : 0.f;
    float invh = dh > 0 ? 1.f / (float)dh : 0.f;
    t += (dg > 0 ? sbg[ch] : 0.f) + (dh > 0 ? sbh[ch] : 0.f) + invg * sg + invh * sh;
    float hid = fmaxf(t, 0.f);

    float pf = sbf[ch];
#pragma unroll
    for (int h = 0; h < HD; h++) pf = fmaf(__shfl(hid, h, 32), sN[h * 32 + ch], pf);
    float hi = __shfl_xor(pf, 1, 32);
    if (!(ch & 1)) PFga16[(size_t)v * 16 + (ch >> 1)] = packbf2(pf, hi);
}

// ===========================================================================
// ga edge kernel (round-11 structure): one wave per cut node.
// slot = {(tgt<<3)|n, eid}.
// ===========================================================================
__global__ __launch_bounds__(256) void ga_edge_kernel(
    const float* __restrict__ PXga, const unsigned* __restrict__ PFga16,
    const int2* __restrict__ slot_a, const float* __restrict__ ea_a,
    const int* __restrict__ off_a, const int* __restrict__ deg_a,
    const float* __restrict__ gaW1,
    float* __restrict__ Aga, int nA)
{
    int gid = blockIdx.x * 256 + threadIdx.x;
    int a   = gid >> 6;
    int ln  = threadIdx.x & 63;
    if (a >= nA) return;

    float px[HD], acc[HD];
    {
        const float4* pp = reinterpret_cast<const float4*>(PXga + (size_t)a * HD);
#pragma unroll
        for (int q = 0; q < 8; q++) {
            float4 t = pp[q];
            px[4*q+0] = t.x; px[4*q+1] = t.y; px[4*q+2] = t.z; px[4*q+3] = t.w;
        }
    }
#pragma unroll
    for (int ch = 0; ch < HD; ch++) acc[ch] = 0.f;

    int base = off_a[a], d = deg_a[a];
    for (int k = ln; k < d; k += 64) {
        int2 w = slot_a[base + k];
        int t = w.x >> 3, e = w.y;
        const uint4* pr = reinterpret_cast<const uint4*>(PFga16 + (size_t)t * 16);
        uint4 r0 = pr[0], r1 = pr[1], r2 = pr[2], r3 = pr[3];
        const float4* pe = reinterpret_cast<const float4*>(ea_a + (size_t)e * ED);
        float4 q0 = pe[0], q1 = pe[1];
        float pf[HD], ev[ED];
        unpack8(r0, pf + 0); unpack8(r1, pf + 8);
        unpack8(r2, pf + 16); unpack8(r3, pf + 24);
        ev[0]=q0.x; ev[1]=q0.y; ev[2]=q0.z; ev[3]=q0.w;
        ev[4]=q1.x; ev[5]=q1.y; ev[6]=q1.z; ev[7]=q1.w;
#pragma unroll
        for (int ch = 0; ch < HD; ch++) {
            float t2 = px[ch] + pf[ch];
#pragma unroll
            for (int i = 0; i < ED; i++) t2 = fmaf(ev[i], gaW1[(ND + HD + i) * HD + ch], t2);
            acc[ch] += fmaxf(t2, 0.f);
        }
    }
#pragma unroll
    for (int m = 1; m < 64; m <<= 1) {
#pragma unroll
        for (int ch = 0; ch < HD; ch++) acc[ch] += __shfl_xor(acc[ch], m, 64);
    }
    if (ln == 0) {
        float4* dst = reinterpret_cast<float4*>(Aga + (size_t)a * HD);
#pragma unroll
        for (int q = 0; q < 8; q++)
            dst[q] = make_float4(acc[4*q+0], acc[4*q+1], acc[4*q+2], acc[4*q+3]);
    }
}

// ===========================================================================
// fa node kernel, CHANNEL-PARALLEL (unchanged from round 11).
// ===========================================================================
__global__ __launch_bounds__(256) void fa_node_kernel(
    const float* __restrict__ xa,
    const float* __restrict__ Aga, const int* __restrict__ deg_a,
    const float* __restrict__ faW1, const float* __restrict__ fab1,
    const float* __restrict__ faW2, const float* __restrict__ fab2,
    const float* __restrict__ Mga, const float* __restrict__ bga,
    float* __restrict__ out, int nA)
{
    __shared__ float sM[1024], sW2[1024], sF[512];
    __shared__ float sbga[32], sb1[32], sb2[32];
    for (int i = threadIdx.x; i < 1024; i += 256) { sM[i] = Mga[i]; sW2[i] = faW2[i]; }
    for (int i = threadIdx.x; i < 512; i += 256) sF[i] = faW1[i];
    if (threadIdx.x < 32) {
        sbga[threadIdx.x] = bga[threadIdx.x];
        sb1[threadIdx.x]  = fab1[threadIdx.x];
        sb2[threadIdx.x]  = fab2[threadIdx.x];
    }
    __syncthreads();

    int gid = blockIdx.x * 256 + threadIdx.x;
    int a = gid >> 5, ch = threadIdx.x & 31;
    if (a >= nA) return;

    float x = (ch < ND) ? xa[(size_t)a * ND + ch] : 0.f;
    float t = sb1[ch];
#pragma unroll
    for (int i = 0; i < ND; i++) t = fmaf(__shfl(x, i, 32), sF[i * 32 + ch], t);

    float agr[HD];
    {
        const float4* pg4 = reinterpret_cast<const float4*>(Aga + (size_t)a * HD);
#pragma unroll
        for (int q = 0; q < 8; q++) {
            float4 w = pg4[q];
            agr[4*q+0] = w.x; agr[4*q+1] = w.y; agr[4*q+2] = w.z; agr[4*q+3] = w.w;
        }
    }
    float s = 0.f;
#pragma unroll
    for (int c = 0; c < HD; c++) s = fmaf(agr[c], sM[c * 32 + ch], s);
    int d = deg_a[a];
    float inv = d > 0 ? 1.f / (float)d : 0.f;
    t += (d > 0 ? sbga[ch] : 0.f) + inv * s;
    float hid = fmaxf(t, 0.f);

    float o = sb2[ch];
#pragma unroll
    for (int h = 0; h < HD; h++) o = fmaf(__shfl(hid, h, 32), sW2[h * 32 + ch], o);
    out[(size_t)a * HD + ch] = o;
}

// ===========================================================================
extern "C" void kernel_launch(void* const* d_in, const int* in_sizes, int n_in,
                              void* d_out, int out_size, void* d_ws, size_t ws_size,
                              hipStream_t stream) {
    const float* x_c    = (const float*)d_in[0];
    const float* x_v    = (const float*)d_in[1];
    const float* x_a    = (const float*)d_in[2];
    const int*   ei_c2v = (const int*)d_in[3];
    const int*   ei_a2v = (const int*)d_in[4];
    const float* ea_c2v = (const float*)d_in[5];
    const float* ea_a2v = (const float*)d_in[6];
    const float *gv_W1=(const float*)d_in[7],  *gv_b1=(const float*)d_in[8],
                *gv_W2=(const float*)d_in[9],  *gv_b2=(const float*)d_in[10];
    const float *hv_W1=(const float*)d_in[11], *hv_b1=(const float*)d_in[12],
                *hv_W2=(const float*)d_in[13], *hv_b2=(const float*)d_in[14];
    const float *fv_W1=(const float*)d_in[15], *fv_b1=(const float*)d_in[16],
                *fv_W2=(const float*)d_in[17], *fv_b2=(const float*)d_in[18];
    const float *ga_W1=(const float*)d_in[19], *ga_b1=(const float*)d_in[20],
                *ga_W2=(const float*)d_in[21], *ga_b2=(const float*)d_in[22];
    const float *fa_W1=(const float*)d_in[23], *fa_b1=(const float*)d_in[24],
                *fa_W2=(const float*)d_in[25], *fa_b2=(const float*)d_in[26];

    const int NC = in_sizes[0] / ND;
    const int NV = in_sizes[1] / ND;
    const int NA = in_sizes[2] / ND;
    const int EC = in_sizes[3] / 2;
    const int EA = in_sizes[4] / 2;
    (void)n_in; (void)out_size; (void)ws_size;

    const int* c2v_s = ei_c2v;            // constraint side of c2v
    const int* c2v_t = ei_c2v + EC;       // variable side
    const int* a2v_s = ei_a2v;            // cut node side
    const int* a2v_t = ei_a2v + EA;       // variable side

    const int nbg = (NV + BKV - 1) / BKV;
    const int nbh = nbg;
    const int nba = (NA + BKA - 1) / BKA;
    const int nb  = nbg + nbh + nba;

    // Workspace layout (4B words)
    int* wsI = (int*)d_ws;
    int* deg_g = wsI;                 // NV
    int* deg_h = deg_g + NV;          // NV
    int* deg_a = deg_h + NV;          // NA
    int* off_g = deg_a + NA;          // NV
    int* off_h = off_g + NV;          // NV
    int* off_a = off_h + NV;          // NA
    int* Bcnt  = off_a + NA;          // nb
    int* Boff  = Bcnt + nb;           // nb
    int* cntg  = Boff + nb;                      // NCHK*nbg
    int* cnth  = cntg + (size_t)NCHK * nbg;      // NCHK*nbh
    int* cnta  = cnth + (size_t)NCHK * nbh;      // NCHK*nba
    int* endcnt = cnta + (size_t)NCHK * nba;
    size_t words = (size_t)(endcnt - wsI);
    if (words & 1) words++;                      // 8B-align slots
    int2* slotU_g = (int2*)(wsI + words);   // EC (unsorted-in-bucket)
    int2* slotU_h = slotU_g + EC;           // EA
    int2* slotU_a = slotU_h + EA;           // EA
    int2* slotS_g = slotU_a + EA;           // EC (node-sorted)
    int2* slotS_h = slotS_g + EC;           // EA
    int2* slotS_a = slotS_h + EA;           // EA
    float* PXg = (float*)(slotS_a + EA);    // NV*32 (aliased as PFga16 later)
    float* PXh = PXg + (size_t)NV * HD;     // NV*32
    float* PXga= PXh + (size_t)NV * HD;     // NA*32
    float* Ag  = PXga + (size_t)NA * HD;    // NV*32
    float* Ah  = Ag + (size_t)NV * HD;      // NV*32
    float* Aga = Ah + (size_t)NV * HD;      // NA*32
    unsigned* PCg16 = (unsigned*)(Aga + (size_t)NA * HD);  // NC*16
    unsigned* PAh16 = PCg16 + (size_t)NC * 16;             // NA*16
    float* Mg  = (float*)(PAh16 + (size_t)NA * 16);        // 1024
    float* Mh  = Mg + HD * HD;            // 1024
    float* Mga = Mh + HD * HD;            // 1024
    float* Nfv = Mga + HD * HD;           // 1024
    float* bgv = Nfv + HD * HD;           // 32
    float* bhv = bgv + HD;                // 32
    float* bgav= bhv + HD;                // 32
    float* bfv = bgav + HD;               // 32
    unsigned* PFga16 = (unsigned*)PXg;    // alias: PXg dead after fv_edge

    // standalone precompute (independent of sort)
    {
        int bV = (NV * 32 + 255) / 256, bC = (NC * 32 + 255) / 256, bA = (NA * 32 + 255) / 256;
        precompC_kernel<<<bV + bC + bA + 4, 256, 0, stream>>>(
            x_v, x_c, x_a,
            gv_W1, gv_b1, hv_W1, hv_b1, ga_W1, ga_b1,
            gv_W2, gv_b2, hv_W2, hv_b2, ga_W2, ga_b2,
            fv_W1, fv_W2, fv_b2, fa_W1,
            PXg, PXh, PXga, PCg16, PAh16,
            Mg, bgv, Mh, bhv, Mga, bgav, Nfv, bfv, NV, NC, NA);
    }

    // bucket histogram (streams read once)
    countB_kernel<<<2 * NCHK, 256, 0, stream>>>(
        c2v_t, cntg, EC, a2v_t, a2v_s, cnth, cnta, EA, nbg, nbh, nba);

    // bucket totals -> offsets -> per-(chunk,bucket) bases
    bsum_kernel<<<(nb + 255) / 256, 256, 0, stream>>>(
        cntg, cnth, cnta, Bcnt, Boff, nbg, nbh, nba);
    bscan_kernel<<<3, 1024, 0, stream>>>(Boff, nbg, nbh, nba);
    bbase_kernel<<<(nb + 255) / 256, 256, 0, stream>>>(
        cntg, cnth, cnta, Boff, nbg, nbh, nba);

    // bucket scatter (contiguous runs per block-bucket)
    scatterBk_kernel<<<2 * NCHK, 256, 0, stream>>>(
        c2v_t, c2v_s, cntg, slotU_g, EC,
        a2v_t, a2v_s, cnth, cnta, slotU_h, slotU_a, EA, nbg, nbh, nba);

    // in-bucket counting sort -> node-sorted slots + per-node deg/off
    bsort_kernel<<<nb, 256, 0, stream>>>(
        slotU_g, slotU_h, slotU_a, slotS_g, slotS_h, slotS_a,
        Boff, Bcnt, deg_g, deg_h, deg_a, off_g, off_h, off_a,
        nbg, nbh, nba, NV, NA);

    // variable-node edge aggregation (8 lanes/node, register acc)
    fv_edge_kernel<<<(NV * 8 + 255) / 256, 256, 0, stream>>>(
        PXg, PCg16, PXh, PAh16, slotS_g, slotS_h, ea_c2v, ea_a2v,
        off_g, deg_g, off_h, deg_h, gv_W1, hv_W1, Ag, Ah, NV);

    // variable-node MLP -> PFga16
    fv_node_kernel<<<(NV * 32 + 255) / 256, 256, 0, stream>>>(
        x_v, Ag, Ah, deg_g, deg_h,
        fv_W1, fv_b1, Mg, bgv, Mh, bhv, Nfv, bfv, PFga16, NV);

    // cut-node edge aggregation (wave/node, register acc)
    ga_edge_kernel<<<(NA * 64 + 255) / 256, 256, 0, stream>>>(
        PXga, PFga16, slotS_a, ea_a2v,
        off_a, deg_a, ga_W1, Aga, NA);

    // cut-node MLP -> output
    fa_node_kernel<<<(NA * 32 + 255) / 256, 256, 0, stream>>>(
        x_a, Aga, deg_a,
        fa_W1, fa_b1, fa_W2, fa_b2, Mga, bgav, (float*)d_out, NA);
}